// Round 3
// baseline (12980.933 us; speedup 1.0000x reference)
//
#include <hip/hip_runtime.h>
#include <hip/hip_bf16.h>
#include <stdint.h>

#define B_ 4096
#define D_ 64
#define T_ 8
#define H_ 128
#define K_ 32
#define NC_ 10
#define M_ 14

#define P_OFF (B_*NC_*T_)            /* 327680 */
#define N_OFF (P_OFF + B_*T_)        /* 360448 */
#define SX_OFF (N_OFF + B_*T_)       /* 393216 */

// ---------------- Threefry-2x32 (20 rounds), exactly JAX's ----------------
__device__ __forceinline__ void tf2x32(uint32_t k0, uint32_t k1,
                                       uint32_t c0, uint32_t c1,
                                       uint32_t& o0, uint32_t& o1) {
  uint32_t ks2 = k0 ^ k1 ^ 0x1BD11BDAu;
  uint32_t x0 = c0 + k0, x1 = c1 + k1;
#define TF_R(r) { x0 += x1; x1 = ((x1 << (r)) | (x1 >> (32 - (r)))); x1 ^= x0; }
  TF_R(13) TF_R(15) TF_R(26) TF_R(6)
  x0 += k1; x1 += ks2 + 1u;
  TF_R(17) TF_R(29) TF_R(16) TF_R(24)
  x0 += ks2; x1 += k0 + 2u;
  TF_R(13) TF_R(15) TF_R(26) TF_R(6)
  x0 += k0; x1 += k1 + 3u;
  TF_R(17) TF_R(29) TF_R(16) TF_R(24)
  x0 += k1; x1 += ks2 + 4u;
  TF_R(13) TF_R(15) TF_R(26) TF_R(6)
  x0 += ks2; x1 += k0 + 5u;
#undef TF_R
  o0 = x0; o1 = x1;
}

// XLA ErfInv32 (Giles single-precision polynomial)
__device__ __forceinline__ float erfinv_f(float x) {
  float w = -log1pf(-x * x);
  float p;
  if (w < 5.0f) {
    w -= 2.5f;
    p = 2.81022636e-08f;
    p = fmaf(p, w, 3.43273939e-07f);
    p = fmaf(p, w, -3.5233877e-06f);
    p = fmaf(p, w, -4.39150654e-06f);
    p = fmaf(p, w, 0.00021858087f);
    p = fmaf(p, w, -0.00125372503f);
    p = fmaf(p, w, -0.00417768164f);
    p = fmaf(p, w, 0.246640727f);
    p = fmaf(p, w, 1.50140941f);
  } else {
    w = sqrtf(w) - 3.0f;
    p = -0.000200214257f;
    p = fmaf(p, w, 0.000100950558f);
    p = fmaf(p, w, 0.00134934322f);
    p = fmaf(p, w, -0.00367342844f);
    p = fmaf(p, w, 0.00573950773f);
    p = fmaf(p, w, -0.0076224613f);
    p = fmaf(p, w, 0.00943887047f);
    p = fmaf(p, w, 1.00167406f);
    p = fmaf(p, w, 2.83297682f);
  }
  return p * x;
}

__device__ __forceinline__ float sigmoid_f(float x) { return 1.0f / (1.0f + expf(-x)); }
__device__ __forceinline__ float softplus_f(float x) {
  return (x > 0.0f) ? (x + log1pf(expf(-x))) : log1pf(expf(x));
}

__launch_bounds__(256, 1)
__global__ void vrnn_kernel(const float* __restrict__ x, const float* __restrict__ sx,
                            const float* __restrict__ Wih, const float* __restrict__ Whh,
                            const float* __restrict__ bih, const float* __restrict__ bhh,
                            const float* __restrict__ We, const float* __restrict__ be,
                            const float* __restrict__ Wl, const float* __restrict__ bl,
                            const float* __restrict__ Wo, const float* __restrict__ bo,
                            const float* __restrict__ Whalt, const float* __restrict__ bhalt,
                            float* __restrict__ out) {
  __shared__ float sh_a[H_][64];          // 32 KB: h / h_new / hb / st exchange
  __shared__ float sh_z[K_][64];          // 8 KB
  __shared__ float sh_gi[4][96][64];      // 98.3 KB: per-wave gate-slice gi cache (per step)
  __shared__ uint32_t sh_keys[T_ * M_][2];

  const int tid = threadIdx.x;
  const int l = tid & 63;                                   // lane = batch row (divergent)
  const int w = __builtin_amdgcn_readfirstlane(tid) >> 6;   // wave id (SGPR-uniform!)
  const int j0 = w * 32;                                    // this wave's gate-neuron slice
  const int b = (int)blockIdx.x * 64 + l;                   // global batch row

  // ---- precompute the 112 tick keys (once) ----
  // JAX >= 0.5 default: threefry_partitionable=True.
  // split(key(42), 112) fold-like: key_q = (o0, o1) of tf2x32(0, 42, 0, q).
  if (tid < T_ * M_) {
    uint32_t o0, o1;
    tf2x32(0u, 42u, 0u, (uint32_t)tid, o0, o1);
    sh_keys[tid][0] = o0;
    sh_keys[tid][1] = o1;
  }

  // ---- init carry h = sx (registers + LDS copy) ----
  float hb[H_];
#pragma unroll
  for (int k = 0; k < H_; ++k) hb[k] = sx[b * H_ + k];
#pragma unroll
  for (int jj = 0; jj < 32; ++jj) sh_a[j0 + jj][l] = sx[b * H_ + j0 + jj];
  __syncthreads();

#pragma unroll 1
  for (int t = 0; t < T_; ++t) {
    // ---- per-step: gi = x_t @ Wih.T + bih (this wave's 96 gate rows) ----
    float xr[D_];
#pragma unroll
    for (int d = 0; d < D_; ++d) xr[d] = x[b * (D_ * T_) + d * T_ + t];
#pragma unroll 1
    for (int gate = 0; gate < 3; ++gate) {
#pragma unroll 1
      for (int jj = 0; jj < 32; ++jj) {
        int j = gate * H_ + j0 + jj;
        float acc = bih[j];
        const float* wp = Wih + j * D_;
#pragma unroll
        for (int d = 0; d < D_; ++d) acc = fmaf(wp[d], xr[d], acc);
        sh_gi[w][gate * 32 + jj][l] = acc;
      }
    }
    // per-step accumulators
    float st[32];
#pragma unroll
    for (int jj = 0; jj < 32; ++jj) st[jj] = 0.0f;
    float yt0 = 0.0f, yt1 = 0.0f, yt2 = 0.0f;
    float csum = 0.0f, pmprev = 0.0f, rt = 0.0f;
    int nt = -1;
    __syncthreads();  // gi ready; prev-step sh_a reads done

#pragma unroll 1
    for (int m = 0; m < M_; ++m) {
      // ---- P1: gh = h @ Whh.T + bhh (slice), GRU gates, h_new -> sh_a ----
#pragma unroll 1
      for (int jj = 0; jj < 32; ++jj) {
        int j = j0 + jj;
        float ar = bhh[j], az = bhh[H_ + j], an = bhh[2 * H_ + j];
        const float* wr = Whh + j * H_;
        const float* wz = Whh + (H_ + j) * H_;
        const float* wn = Whh + (2 * H_ + j) * H_;
#pragma unroll
        for (int k = 0; k < H_; ++k) {
          ar = fmaf(wr[k], hb[k], ar);
          az = fmaf(wz[k], hb[k], az);
          an = fmaf(wn[k], hb[k], an);
        }
        float gir = sh_gi[w][jj][l];
        float giz = sh_gi[w][32 + jj][l];
        float gin = sh_gi[w][64 + jj][l];
        float r = sigmoid_f(gir + ar);
        float zg = sigmoid_f(giz + az);
        float n = tanhf(fmaf(r, an, gin));
        float hprev = sh_a[j][l];            // dynamic index -> LDS, not regs
        sh_a[j][l] = (1.0f - zg) * n + zg * hprev;
      }
      __syncthreads();

      // ---- P2: h_new -> regs; enc slice; z draws (threefry+erfinv) -> sh_z ----
#pragma unroll
      for (int k = 0; k < H_; ++k) hb[k] = sh_a[k][l];
      {
        uint32_t key0 = sh_keys[t * M_ + m][0];
        uint32_t key1 = sh_keys[t * M_ + m][1];
#pragma unroll 1
        for (int i = 0; i < 8; ++i) {
          int kd = j0 / 4 + i;  // = w*8 + i
          float accM = be[kd], accS = be[K_ + kd];
          const float* wm = We + kd * H_;
          const float* ws = We + (K_ + kd) * H_;
#pragma unroll
          for (int k = 0; k < H_; ++k) {
            accM = fmaf(wm[k], hb[k], accM);
            accS = fmaf(ws[k], hb[k], accS);
          }
          float sg = softplus_f(accS - 5.0f);
          // partitionable random_bits: counter (hi,lo) = (0, flat_idx); bits = o0^o1
          uint32_t e = (uint32_t)b * 32u + (uint32_t)kd;
          uint32_t r0, r1;
          tf2x32(key0, key1, 0u, e, r0, r1);
          uint32_t bits = r0 ^ r1;
          float f = __uint_as_float((bits >> 9) | 0x3f800000u) - 1.0f;
          float u = fmaf(f, 2.0f, -0.99999994f);   // span rounds to exactly 2.0f
          u = fmaxf(-0.99999994f, u);
          float eps = 1.41421356f * erfinv_f(u);   // f32(sqrt(2)) * erfinv
          sh_z[kd][l] = fmaf(eps, sg, accM);
        }
      }
      __syncthreads();

      // ---- P3: hb_new slice = tanh(z @ Wl.T + bl) -> sh_a ----
      {
        float zr[K_];
#pragma unroll
        for (int k = 0; k < K_; ++k) zr[k] = sh_z[k][l];
#pragma unroll 1
        for (int jj = 0; jj < 32; ++jj) {
          int j = j0 + jj;
          float v = bl[j];
          const float* wl = Wl + j * K_;
#pragma unroll
          for (int k = 0; k < K_; ++k) v = fmaf(wl[k], zr[k], v);
          sh_a[j][l] = tanhf(v);
        }
      }
      __syncthreads();

      // ---- P4: hb -> regs; pn; y slice; halting update; st/yt accumulate ----
#pragma unroll
      for (int k = 0; k < H_; ++k) hb[k] = sh_a[k][l];
      float pa = bhalt[0];
#pragma unroll
      for (int k = 0; k < H_; ++k) pa = fmaf(Whalt[k], hb[k], pa);
      float pn = sigmoid_f(pa);

      float yv[3];
#pragma unroll
      for (int i = 0; i < 3; ++i) {
        int c = w + 4 * i;
        float a = 0.0f;
        if (c < NC_) {
          a = bo[c];
          const float* wo = Wo + c * H_;
#pragma unroll
          for (int k = 0; k < H_; ++k) a = fmaf(wo[k], hb[k], a);
        }
        yv[i] = a;
      }

      csum += pn;
      float pm = (m == M_ - 1) ? 1.0f : fminf(1.0f, csum);
      if (nt < 0 && (csum >= 1.0f || m == M_ - 1)) {
        nt = m;
        rt = (m == 0) ? 0.0f : (1.0f - pmprev);
      }
      float ph = pm - pmprev;
      pmprev = pm;
#pragma unroll
      for (int jj = 0; jj < 32; ++jj) st[jj] = fmaf(ph, sh_a[j0 + jj][l], st[jj]);
      yt0 = fmaf(ph, yv[0], yt0);
      yt1 = fmaf(ph, yv[1], yt1);
      yt2 = fmaf(ph, yv[2], yt2);
      __syncthreads();
    }  // ticks

    // ---- step end: st -> sh_a (next carry), write outputs (FLOAT32) ----
#pragma unroll
    for (int jj = 0; jj < 32; ++jj) sh_a[j0 + jj][l] = st[jj];
#pragma unroll
    for (int i = 0; i < 3; ++i) {
      int c = w + 4 * i;
      float ytv = (i == 0) ? yt0 : ((i == 1) ? yt1 : yt2);
      if (c < NC_) out[b * (NC_ * T_) + c * T_ + t] = ytv;
    }
    if (w == 0) {
      out[P_OFF + b * T_ + t] = (float)nt + rt;
      out[N_OFF + b * T_ + t] = (float)nt;
    }
    if (t == T_ - 1) {
#pragma unroll
      for (int jj = 0; jj < 32; ++jj)
        out[SX_OFF + b * H_ + j0 + jj] = st[jj];
    }
    __syncthreads();
#pragma unroll
    for (int k = 0; k < H_; ++k) hb[k] = sh_a[k][l];
  }  // steps
}

extern "C" void kernel_launch(void* const* d_in, const int* in_sizes, int n_in,
                              void* d_out, int out_size, void* d_ws, size_t ws_size,
                              hipStream_t stream) {
  (void)in_sizes; (void)n_in; (void)out_size; (void)d_ws; (void)ws_size;
  const float* x     = (const float*)d_in[0];
  const float* sx    = (const float*)d_in[1];
  const float* Wih   = (const float*)d_in[2];
  const float* Whh   = (const float*)d_in[3];
  const float* bih   = (const float*)d_in[4];
  const float* bhh   = (const float*)d_in[5];
  const float* We    = (const float*)d_in[6];
  const float* be    = (const float*)d_in[7];
  const float* Wl    = (const float*)d_in[8];
  const float* bl    = (const float*)d_in[9];
  const float* Wo    = (const float*)d_in[10];
  const float* bo    = (const float*)d_in[11];
  const float* Whalt = (const float*)d_in[12];
  const float* bhalt = (const float*)d_in[13];
  float* out = (float*)d_out;

  vrnn_kernel<<<dim3(64), dim3(256), 0, stream>>>(x, sx, Wih, Whh, bih, bhh,
                                                  We, be, Wl, bl, Wo, bo,
                                                  Whalt, bhalt, out);
}

// Round 4
// 5108.630 us; speedup vs baseline: 2.5410x; 2.5410x over previous
//
#include <hip/hip_runtime.h>
#include <hip/hip_bf16.h>
#include <stdint.h>

#define B_ 4096
#define D_ 64
#define T_ 8
#define H_ 128
#define K_ 32
#define NC_ 10
#define M_ 14

#define P_OFF (B_*NC_*T_)            /* 327680 */
#define N_OFF (P_OFF + B_*T_)        /* 360448 */
#define SX_OFF (N_OFF + B_*T_)       /* 393216 */

// ---------------- Threefry-2x32 (20 rounds), exactly JAX's ----------------
__device__ __forceinline__ void tf2x32(uint32_t k0, uint32_t k1,
                                       uint32_t c0, uint32_t c1,
                                       uint32_t& o0, uint32_t& o1) {
  uint32_t ks2 = k0 ^ k1 ^ 0x1BD11BDAu;
  uint32_t x0 = c0 + k0, x1 = c1 + k1;
#define TF_R(r) { x0 += x1; x1 = ((x1 << (r)) | (x1 >> (32 - (r)))); x1 ^= x0; }
  TF_R(13) TF_R(15) TF_R(26) TF_R(6)
  x0 += k1; x1 += ks2 + 1u;
  TF_R(17) TF_R(29) TF_R(16) TF_R(24)
  x0 += ks2; x1 += k0 + 2u;
  TF_R(13) TF_R(15) TF_R(26) TF_R(6)
  x0 += k0; x1 += k1 + 3u;
  TF_R(17) TF_R(29) TF_R(16) TF_R(24)
  x0 += k1; x1 += ks2 + 4u;
  TF_R(13) TF_R(15) TF_R(26) TF_R(6)
  x0 += ks2; x1 += k0 + 5u;
#undef TF_R
  o0 = x0; o1 = x1;
}

// XLA ErfInv32 (Giles single-precision polynomial)
__device__ __forceinline__ float erfinv_f(float x) {
  float w = -log1pf(-x * x);
  float p;
  if (w < 5.0f) {
    w -= 2.5f;
    p = 2.81022636e-08f;
    p = fmaf(p, w, 3.43273939e-07f);
    p = fmaf(p, w, -3.5233877e-06f);
    p = fmaf(p, w, -4.39150654e-06f);
    p = fmaf(p, w, 0.00021858087f);
    p = fmaf(p, w, -0.00125372503f);
    p = fmaf(p, w, -0.00417768164f);
    p = fmaf(p, w, 0.246640727f);
    p = fmaf(p, w, 1.50140941f);
  } else {
    w = sqrtf(w) - 3.0f;
    p = -0.000200214257f;
    p = fmaf(p, w, 0.000100950558f);
    p = fmaf(p, w, 0.00134934322f);
    p = fmaf(p, w, -0.00367342844f);
    p = fmaf(p, w, 0.00573950773f);
    p = fmaf(p, w, -0.0076224613f);
    p = fmaf(p, w, 0.00943887047f);
    p = fmaf(p, w, 1.00167406f);
    p = fmaf(p, w, 2.83297682f);
  }
  return p * x;
}

__device__ __forceinline__ float sigmoid_f(float x) { return 1.0f / (1.0f + expf(-x)); }
__device__ __forceinline__ float softplus_f(float x) {
  return (x > 0.0f) ? (x + log1pf(expf(-x))) : log1pf(expf(x));
}

// 256 blocks x 256 threads. Block owns 16 batch rows.
// thread: r = tid&15 (batch row), idx = tid>>4 (0..15 work slice).
// idx owns: hidden neurons [idx*8, idx*8+8), latent neurons [idx*2, idx*2+2),
//           y class idx (if <10), pn computed redundantly by all.
__launch_bounds__(256, 1)
__global__ void vrnn_kernel(const float* __restrict__ x, const float* __restrict__ sx,
                            const float* __restrict__ Wih, const float* __restrict__ Whh,
                            const float* __restrict__ bih, const float* __restrict__ bhh,
                            const float* __restrict__ We, const float* __restrict__ be,
                            const float* __restrict__ Wl, const float* __restrict__ bl,
                            const float* __restrict__ Wo, const float* __restrict__ bo,
                            const float* __restrict__ Whalt, const float* __restrict__ bhalt,
                            float* __restrict__ out) {
  __shared__ float sh_h[16][132];        // 8.4 KB, padded: 2-way max on b128 reads
  __shared__ float sh_z[16][36];         // 2.3 KB
  __shared__ uint32_t sh_keys[T_ * M_][2];

  const int tid = threadIdx.x;
  const int r = tid & 15;
  const int idx = tid >> 4;              // 0..15
  const int i0 = idx * 8;                // hidden slice
  const int kd0 = idx * 2;               // latent slice
  const int b = (int)blockIdx.x * 16 + r;

  // JAX >=0.5 partitionable split: key_q = threefry(key, (0, q))
  if (tid < T_ * M_) {
    uint32_t o0, o1;
    tf2x32(0u, 42u, 0u, (uint32_t)tid, o0, o1);
    sh_keys[tid][0] = o0;
    sh_keys[tid][1] = o1;
  }

  float hb[H_];
#pragma unroll
  for (int k = 0; k < H_; ++k) hb[k] = sx[b * H_ + k];
#pragma unroll
  for (int ii = 0; ii < 8; ++ii) sh_h[r][i0 + ii] = hb[i0 + ii];
  __syncthreads();

  float gi[24];

#pragma unroll 1
  for (int t = 0; t < T_; ++t) {
    // ---- per-step gi for owned neurons (kept in regs across the tick loop) ----
    {
      float xr[D_];
#pragma unroll
      for (int d = 0; d < D_; ++d) xr[d] = x[b * (D_ * T_) + d * T_ + t];
#pragma unroll 1
      for (int ii = 0; ii < 8; ++ii) {
        int i = i0 + ii;
        float a0 = bih[i], a1 = bih[H_ + i], a2 = bih[2 * H_ + i];
        const float* w0 = Wih + i * D_;
        const float* w1 = Wih + (H_ + i) * D_;
        const float* w2 = Wih + (2 * H_ + i) * D_;
#pragma unroll
        for (int d = 0; d < D_; ++d) {
          a0 = fmaf(w0[d], xr[d], a0);
          a1 = fmaf(w1[d], xr[d], a1);
          a2 = fmaf(w2[d], xr[d], a2);
        }
        gi[ii] = a0; gi[8 + ii] = a1; gi[16 + ii] = a2;
      }
    }

    float st[8];
#pragma unroll
    for (int ii = 0; ii < 8; ++ii) st[ii] = 0.0f;
    float yt = 0.0f;
    float csum = 0.0f, pmprev = 0.0f, rt = 0.0f;
    int nt = -1;

#pragma unroll 1
    for (int m = 0; m < M_; ++m) {
      // ---- P1: gh slice + local gate-combine -> hnew ----
      float hn[8];
#pragma unroll 1
      for (int ii = 0; ii < 8; ++ii) {
        int i = i0 + ii;
        float ar = bhh[i], az = bhh[H_ + i], an = bhh[2 * H_ + i];
        const float* wr = Whh + i * H_;
        const float* wz = Whh + (H_ + i) * H_;
        const float* wn = Whh + (2 * H_ + i) * H_;
#pragma unroll
        for (int k = 0; k < H_; ++k) {
          ar = fmaf(wr[k], hb[k], ar);
          az = fmaf(wz[k], hb[k], az);
          an = fmaf(wn[k], hb[k], an);
        }
        float rg = sigmoid_f(gi[ii] + ar);
        float zg = sigmoid_f(gi[8 + ii] + az);
        float ng = tanhf(fmaf(rg, an, gi[16 + ii]));
        hn[ii] = (1.0f - zg) * ng + zg * hb[i];
      }
#pragma unroll
      for (int ii = 0; ii < 8; ++ii) sh_h[r][i0 + ii] = hn[ii];
      __syncthreads();

      // ---- refill hb = hnew; P2: enc slice + z draws ----
#pragma unroll
      for (int k = 0; k < H_; ++k) hb[k] = sh_h[r][k];
      {
        uint32_t key0 = sh_keys[t * M_ + m][0];
        uint32_t key1 = sh_keys[t * M_ + m][1];
#pragma unroll 1
        for (int q = 0; q < 2; ++q) {
          int kd = kd0 + q;
          float accM = be[kd], accS = be[K_ + kd];
          const float* wm = We + kd * H_;
          const float* ws = We + (K_ + kd) * H_;
#pragma unroll
          for (int k = 0; k < H_; ++k) {
            accM = fmaf(wm[k], hb[k], accM);
            accS = fmaf(ws[k], hb[k], accS);
          }
          float sg = softplus_f(accS - 5.0f);
          uint32_t e = (uint32_t)b * 32u + (uint32_t)kd;
          uint32_t r0, r1;
          tf2x32(key0, key1, 0u, e, r0, r1);
          uint32_t bits = r0 ^ r1;
          float f = __uint_as_float((bits >> 9) | 0x3f800000u) - 1.0f;
          float u = fmaf(f, 2.0f, -0.99999994f);
          u = fmaxf(-0.99999994f, u);
          float eps = 1.41421356f * erfinv_f(u);
          sh_z[r][kd] = fmaf(eps, sg, accM);
        }
      }
      __syncthreads();

      // ---- P3: hb2 slice = tanh(z @ Wl.T + bl) ----
      {
        float zr[K_];
#pragma unroll
        for (int k = 0; k < K_; ++k) zr[k] = sh_z[r][k];
#pragma unroll 1
        for (int ii = 0; ii < 8; ++ii) {
          int i = i0 + ii;
          float v = bl[i];
          const float* wl = Wl + i * K_;
#pragma unroll
          for (int k = 0; k < K_; ++k) v = fmaf(wl[k], zr[k], v);
          hn[ii] = tanhf(v);
          sh_h[r][i] = hn[ii];
        }
      }
      __syncthreads();

      // ---- refill hb = hb2; P4: pn (all), y (idx<10), halting, accumulate ----
#pragma unroll
      for (int k = 0; k < H_; ++k) hb[k] = sh_h[r][k];
      float pa = bhalt[0];
#pragma unroll
      for (int k = 0; k < H_; ++k) pa = fmaf(Whalt[k], hb[k], pa);
      float pn = sigmoid_f(pa);

      float yv = 0.0f;
      if (idx < NC_) {
        yv = bo[idx];
        const float* wo = Wo + idx * H_;
#pragma unroll
        for (int k = 0; k < H_; ++k) yv = fmaf(wo[k], hb[k], yv);
      }

      csum += pn;
      float pm = (m == M_ - 1) ? 1.0f : fminf(1.0f, csum);
      if (nt < 0 && (csum >= 1.0f || m == M_ - 1)) {
        nt = m;
        rt = (m == 0) ? 0.0f : (1.0f - pmprev);
      }
      float ph = pm - pmprev;
      pmprev = pm;
#pragma unroll
      for (int ii = 0; ii < 8; ++ii) st[ii] = fmaf(ph, hn[ii], st[ii]);
      yt = fmaf(ph, yv, yt);
      __syncthreads();
    }  // ticks

    // ---- step end: st becomes next h; write outputs ----
#pragma unroll
    for (int ii = 0; ii < 8; ++ii) sh_h[r][i0 + ii] = st[ii];
    if (idx < NC_) out[b * (NC_ * T_) + idx * T_ + t] = yt;
    if (idx == 10) {
      out[P_OFF + b * T_ + t] = (float)nt + rt;
      out[N_OFF + b * T_ + t] = (float)nt;
    }
    if (t == T_ - 1) {
#pragma unroll
      for (int ii = 0; ii < 8; ++ii)
        out[SX_OFF + b * H_ + i0 + ii] = st[ii];
    }
    __syncthreads();
#pragma unroll
    for (int k = 0; k < H_; ++k) hb[k] = sh_h[r][k];
    __syncthreads();   // protect refill reads from next-step P1's sh_h writes
  }  // steps
}

extern "C" void kernel_launch(void* const* d_in, const int* in_sizes, int n_in,
                              void* d_out, int out_size, void* d_ws, size_t ws_size,
                              hipStream_t stream) {
  (void)in_sizes; (void)n_in; (void)out_size; (void)d_ws; (void)ws_size;
  const float* x     = (const float*)d_in[0];
  const float* sx    = (const float*)d_in[1];
  const float* Wih   = (const float*)d_in[2];
  const float* Whh   = (const float*)d_in[3];
  const float* bih   = (const float*)d_in[4];
  const float* bhh   = (const float*)d_in[5];
  const float* We    = (const float*)d_in[6];
  const float* be    = (const float*)d_in[7];
  const float* Wl    = (const float*)d_in[8];
  const float* bl    = (const float*)d_in[9];
  const float* Wo    = (const float*)d_in[10];
  const float* bo    = (const float*)d_in[11];
  const float* Whalt = (const float*)d_in[12];
  const float* bhalt = (const float*)d_in[13];
  float* out = (float*)d_out;

  vrnn_kernel<<<dim3(256), dim3(256), 0, stream>>>(x, sx, Wih, Whh, bih, bhh,
                                                   We, be, Wl, bl, Wo, bo,
                                                   Whalt, bhalt, out);
}

// Round 5
// 3578.202 us; speedup vs baseline: 3.6278x; 1.4277x over previous
//
#include <hip/hip_runtime.h>
#include <hip/hip_bf16.h>
#include <stdint.h>

#define B_ 4096
#define D_ 64
#define T_ 8
#define H_ 128
#define K_ 32
#define NC_ 10
#define M_ 14

#define P_OFF (B_*NC_*T_)            /* 327680 */
#define N_OFF (P_OFF + B_*T_)        /* 360448 */
#define SX_OFF (N_OFF + B_*T_)       /* 393216 */

#define ROWS 8       /* batch rows per block */
#define NPT 4        /* hidden neurons per thread (32 slices * 4 = 128) */

// ---------------- Threefry-2x32 (20 rounds), exactly JAX's ----------------
__device__ __forceinline__ void tf2x32(uint32_t k0, uint32_t k1,
                                       uint32_t c0, uint32_t c1,
                                       uint32_t& o0, uint32_t& o1) {
  uint32_t ks2 = k0 ^ k1 ^ 0x1BD11BDAu;
  uint32_t x0 = c0 + k0, x1 = c1 + k1;
#define TF_R(r) { x0 += x1; x1 = ((x1 << (r)) | (x1 >> (32 - (r)))); x1 ^= x0; }
  TF_R(13) TF_R(15) TF_R(26) TF_R(6)
  x0 += k1; x1 += ks2 + 1u;
  TF_R(17) TF_R(29) TF_R(16) TF_R(24)
  x0 += ks2; x1 += k0 + 2u;
  TF_R(13) TF_R(15) TF_R(26) TF_R(6)
  x0 += k0; x1 += k1 + 3u;
  TF_R(17) TF_R(29) TF_R(16) TF_R(24)
  x0 += k1; x1 += ks2 + 4u;
  TF_R(13) TF_R(15) TF_R(26) TF_R(6)
  x0 += ks2; x1 += k0 + 5u;
#undef TF_R
  o0 = x0; o1 = x1;
}

// XLA ErfInv32 (Giles single-precision polynomial)
__device__ __forceinline__ float erfinv_f(float x) {
  float w = -log1pf(-x * x);
  float p;
  if (w < 5.0f) {
    w -= 2.5f;
    p = 2.81022636e-08f;
    p = fmaf(p, w, 3.43273939e-07f);
    p = fmaf(p, w, -3.5233877e-06f);
    p = fmaf(p, w, -4.39150654e-06f);
    p = fmaf(p, w, 0.00021858087f);
    p = fmaf(p, w, -0.00125372503f);
    p = fmaf(p, w, -0.00417768164f);
    p = fmaf(p, w, 0.246640727f);
    p = fmaf(p, w, 1.50140941f);
  } else {
    w = sqrtf(w) - 3.0f;
    p = -0.000200214257f;
    p = fmaf(p, w, 0.000100950558f);
    p = fmaf(p, w, 0.00134934322f);
    p = fmaf(p, w, -0.00367342844f);
    p = fmaf(p, w, 0.00573950773f);
    p = fmaf(p, w, -0.0076224613f);
    p = fmaf(p, w, 0.00943887047f);
    p = fmaf(p, w, 1.00167406f);
    p = fmaf(p, w, 2.83297682f);
  }
  return p * x;
}

__device__ __forceinline__ float sigmoid_f(float x) { return 1.0f / (1.0f + expf(-x)); }
__device__ __forceinline__ float softplus_f(float x) {
  return (x > 0.0f) ? (x + log1pf(expf(-x))) : log1pf(expf(x));
}

// 512 blocks x 256 threads. Block owns 8 batch rows.
// thread: r = tid&7 (batch row), idx = tid>>3 (0..31 work slice).
// idx owns: hidden neurons [idx*4, idx*4+4), latent neuron idx,
//           y class idx (if <10). pn computed redundantly by all.
// h is NEVER register-resident: streamed from LDS in float4 chunks.
__launch_bounds__(256, 2)
__global__ void vrnn_kernel(const float* __restrict__ x, const float* __restrict__ sx,
                            const float* __restrict__ Wih, const float* __restrict__ Whh,
                            const float* __restrict__ bih, const float* __restrict__ bhh,
                            const float* __restrict__ We, const float* __restrict__ be,
                            const float* __restrict__ Wl, const float* __restrict__ bl,
                            const float* __restrict__ Wo, const float* __restrict__ bo,
                            const float* __restrict__ Whalt, const float* __restrict__ bhalt,
                            float* __restrict__ out) {
  __shared__ float sh_hA[ROWS][132];     // h carry / hb  (P1,P4 read; P3 write)
  __shared__ float sh_hB[ROWS][132];     // h_gru         (P1 write; P2 read)
  __shared__ float sh_z[ROWS][36];
  __shared__ uint32_t sh_keys[T_ * M_][2];

  const int tid = threadIdx.x;
  const int r = tid & (ROWS - 1);
  const int idx = tid >> 3;              // 0..31
  const int i0 = idx * NPT;              // hidden slice
  const int kd = idx;                    // latent neuron
  const int b = (int)blockIdx.x * ROWS + r;

  // JAX >=0.5 partitionable split: key_q = threefry(key, (0, q))
  if (tid < T_ * M_) {
    uint32_t o0, o1;
    tf2x32(0u, 42u, 0u, (uint32_t)tid, o0, o1);
    sh_keys[tid][0] = o0;
    sh_keys[tid][1] = o1;
  }

  // init h carry = sx
  if (idx < 16) {
#pragma unroll
    for (int q = 0; q < 8; ++q) sh_hA[r][idx * 8 + q] = sx[b * H_ + idx * 8 + q];
  }
  __syncthreads();

  float gi[12];                          // per-step input gates, [g*NPT+ii]

#pragma unroll 1
  for (int t = 0; t < T_; ++t) {
    // ---- per-step gi for owned neurons ----
    {
      float xr[D_];
#pragma unroll
      for (int d = 0; d < D_; ++d) xr[d] = x[b * (D_ * T_) + d * T_ + t];
#pragma unroll 1
      for (int g = 0; g < 3; ++g) {
#pragma unroll
        for (int ii = 0; ii < NPT; ++ii) {
          int j = g * H_ + i0 + ii;
          float acc = bih[j];
          const float* wp = Wih + j * D_;
#pragma unroll
          for (int d = 0; d < D_; ++d) acc = fmaf(wp[d], xr[d], acc);
          gi[g * NPT + ii] = acc;
        }
      }
    }

    float st[NPT];
#pragma unroll
    for (int ii = 0; ii < NPT; ++ii) st[ii] = 0.0f;
    float yt = 0.0f;
    float csum = 0.0f, pmprev = 0.0f, rt = 0.0f;
    int nt = -1;

#pragma unroll 1
    for (int m = 0; m < M_; ++m) {
      // ---- P1: gh slice (stream h from A), gate-combine -> write B ----
      {
        float a[12];
#pragma unroll
        for (int g = 0; g < 3; ++g)
#pragma unroll
          for (int ii = 0; ii < NPT; ++ii) a[g * NPT + ii] = bhh[g * H_ + i0 + ii];
        const float* w0 = Whh + (0 * H_ + i0) * H_;
        const float* w1 = Whh + (1 * H_ + i0) * H_;
        const float* w2 = Whh + (2 * H_ + i0) * H_;
#pragma unroll 2
        for (int kk = 0; kk < H_ / 4; ++kk) {
          float4 hv = *(const float4*)&sh_hA[r][kk * 4];
#pragma unroll
          for (int ii = 0; ii < NPT; ++ii) {
            float4 wv;
            wv = *(const float4*)(w0 + ii * H_ + kk * 4);
            a[0 * NPT + ii] = fmaf(wv.x, hv.x, a[0 * NPT + ii]);
            a[0 * NPT + ii] = fmaf(wv.y, hv.y, a[0 * NPT + ii]);
            a[0 * NPT + ii] = fmaf(wv.z, hv.z, a[0 * NPT + ii]);
            a[0 * NPT + ii] = fmaf(wv.w, hv.w, a[0 * NPT + ii]);
            wv = *(const float4*)(w1 + ii * H_ + kk * 4);
            a[1 * NPT + ii] = fmaf(wv.x, hv.x, a[1 * NPT + ii]);
            a[1 * NPT + ii] = fmaf(wv.y, hv.y, a[1 * NPT + ii]);
            a[1 * NPT + ii] = fmaf(wv.z, hv.z, a[1 * NPT + ii]);
            a[1 * NPT + ii] = fmaf(wv.w, hv.w, a[1 * NPT + ii]);
            wv = *(const float4*)(w2 + ii * H_ + kk * 4);
            a[2 * NPT + ii] = fmaf(wv.x, hv.x, a[2 * NPT + ii]);
            a[2 * NPT + ii] = fmaf(wv.y, hv.y, a[2 * NPT + ii]);
            a[2 * NPT + ii] = fmaf(wv.z, hv.z, a[2 * NPT + ii]);
            a[2 * NPT + ii] = fmaf(wv.w, hv.w, a[2 * NPT + ii]);
          }
        }
#pragma unroll
        for (int ii = 0; ii < NPT; ++ii) {
          float rg = sigmoid_f(gi[ii] + a[ii]);
          float zg = sigmoid_f(gi[NPT + ii] + a[NPT + ii]);
          float ng = tanhf(fmaf(rg, a[2 * NPT + ii], gi[2 * NPT + ii]));
          float hprev = sh_hA[r][i0 + ii];
          sh_hB[r][i0 + ii] = (1.0f - zg) * ng + zg * hprev;
        }
      }
      __syncthreads();

      // ---- P2: enc for latent kd (stream h from B); z draw -> sh_z ----
      {
        float accM = be[kd], accS = be[K_ + kd];
        const float* wm = We + kd * H_;
        const float* ws = We + (K_ + kd) * H_;
#pragma unroll 2
        for (int kk = 0; kk < H_ / 4; ++kk) {
          float4 hv = *(const float4*)&sh_hB[r][kk * 4];
          float4 mv = *(const float4*)(wm + kk * 4);
          float4 sv = *(const float4*)(ws + kk * 4);
          accM = fmaf(mv.x, hv.x, accM); accS = fmaf(sv.x, hv.x, accS);
          accM = fmaf(mv.y, hv.y, accM); accS = fmaf(sv.y, hv.y, accS);
          accM = fmaf(mv.z, hv.z, accM); accS = fmaf(sv.z, hv.z, accS);
          accM = fmaf(mv.w, hv.w, accM); accS = fmaf(sv.w, hv.w, accS);
        }
        float sg = softplus_f(accS - 5.0f);
        uint32_t key0 = sh_keys[t * M_ + m][0];
        uint32_t key1 = sh_keys[t * M_ + m][1];
        uint32_t e = (uint32_t)b * 32u + (uint32_t)kd;
        uint32_t r0, r1;
        tf2x32(key0, key1, 0u, e, r0, r1);
        uint32_t bits = r0 ^ r1;
        float f = __uint_as_float((bits >> 9) | 0x3f800000u) - 1.0f;
        float u = fmaf(f, 2.0f, -0.99999994f);
        u = fmaxf(-0.99999994f, u);
        float eps = 1.41421356f * erfinv_f(u);
        sh_z[r][kd] = fmaf(eps, sg, accM);
      }
      __syncthreads();

      // ---- P3: hb slice = tanh(z @ Wl.T + bl) -> write A ----
      float hn[NPT];
      {
        float zr[K_];
#pragma unroll
        for (int q = 0; q < K_ / 4; ++q) {
          float4 zv = *(const float4*)&sh_z[r][q * 4];
          zr[q * 4] = zv.x; zr[q * 4 + 1] = zv.y; zr[q * 4 + 2] = zv.z; zr[q * 4 + 3] = zv.w;
        }
#pragma unroll
        for (int ii = 0; ii < NPT; ++ii) {
          int i = i0 + ii;
          float v = bl[i];
          const float* wl = Wl + i * K_;
#pragma unroll
          for (int k = 0; k < K_; ++k) v = fmaf(wl[k], zr[k], v);
          hn[ii] = tanhf(v);
          sh_hA[r][i] = hn[ii];
        }
      }
      __syncthreads();

      // ---- P4: pn (all threads, stream A), y (idx<10), halting, accumulate ----
      {
        float pa = bhalt[0];
        float yv = 0.0f;
        const float* wo = Wo + idx * H_;
        bool doy = (idx < NC_);
        if (doy) yv = bo[idx];
#pragma unroll 2
        for (int kk = 0; kk < H_ / 4; ++kk) {
          float4 hv = *(const float4*)&sh_hA[r][kk * 4];
          float4 av = *(const float4*)(Whalt + kk * 4);
          pa = fmaf(av.x, hv.x, pa); pa = fmaf(av.y, hv.y, pa);
          pa = fmaf(av.z, hv.z, pa); pa = fmaf(av.w, hv.w, pa);
          if (doy) {
            float4 ov = *(const float4*)(wo + kk * 4);
            yv = fmaf(ov.x, hv.x, yv); yv = fmaf(ov.y, hv.y, yv);
            yv = fmaf(ov.z, hv.z, yv); yv = fmaf(ov.w, hv.w, yv);
          }
        }
        float pn = sigmoid_f(pa);
        csum += pn;
        float pm = (m == M_ - 1) ? 1.0f : fminf(1.0f, csum);
        if (nt < 0 && (csum >= 1.0f || m == M_ - 1)) {
          nt = m;
          rt = (m == 0) ? 0.0f : (1.0f - pmprev);
        }
        float ph = pm - pmprev;
        pmprev = pm;
#pragma unroll
        for (int ii = 0; ii < NPT; ++ii) st[ii] = fmaf(ph, hn[ii], st[ii]);
        yt = fmaf(ph, yv, yt);
      }
      // no barrier needed here: next P1 only reads A (written pre-barrier in P3)
    }  // ticks

    // ---- step end: st becomes next h carry; write outputs ----
    __syncthreads();   // all P4 reads of A complete before overwrite
#pragma unroll
    for (int ii = 0; ii < NPT; ++ii) sh_hA[r][i0 + ii] = st[ii];
    if (idx < NC_) out[b * (NC_ * T_) + idx * T_ + t] = yt;
    if (idx == 10) {
      out[P_OFF + b * T_ + t] = (float)nt + rt;
      out[N_OFF + b * T_ + t] = (float)nt;
    }
    if (t == T_ - 1) {
#pragma unroll
      for (int ii = 0; ii < NPT; ++ii)
        out[SX_OFF + b * H_ + i0 + ii] = st[ii];
    }
    __syncthreads();   // new carry visible before next step's P1
  }  // steps
}

extern "C" void kernel_launch(void* const* d_in, const int* in_sizes, int n_in,
                              void* d_out, int out_size, void* d_ws, size_t ws_size,
                              hipStream_t stream) {
  (void)in_sizes; (void)n_in; (void)out_size; (void)d_ws; (void)ws_size;
  const float* x     = (const float*)d_in[0];
  const float* sx    = (const float*)d_in[1];
  const float* Wih   = (const float*)d_in[2];
  const float* Whh   = (const float*)d_in[3];
  const float* bih   = (const float*)d_in[4];
  const float* bhh   = (const float*)d_in[5];
  const float* We    = (const float*)d_in[6];
  const float* be    = (const float*)d_in[7];
  const float* Wl    = (const float*)d_in[8];
  const float* bl    = (const float*)d_in[9];
  const float* Wo    = (const float*)d_in[10];
  const float* bo    = (const float*)d_in[11];
  const float* Whalt = (const float*)d_in[12];
  const float* bhalt = (const float*)d_in[13];
  float* out = (float*)d_out;

  vrnn_kernel<<<dim3(B_ / ROWS), dim3(256), 0, stream>>>(x, sx, Wih, Whh, bih, bhh,
                                                         We, be, Wl, bl, Wo, bo,
                                                         Whalt, bhalt, out);
}

// Round 6
// 3506.399 us; speedup vs baseline: 3.7021x; 1.0205x over previous
//
#include <hip/hip_runtime.h>
#include <hip/hip_bf16.h>
#include <stdint.h>

#define B_ 4096
#define D_ 64
#define T_ 8
#define H_ 128
#define K_ 32
#define NC_ 10
#define M_ 14

#define P_OFF (B_*NC_*T_)            /* 327680 */
#define N_OFF (P_OFF + B_*T_)        /* 360448 */
#define SX_OFF (N_OFF + B_*T_)       /* 393216 */

#define ROWS 8       /* batch rows per block */
#define THREADS 512  /* 8 waves; 2 blocks/CU -> 4 waves/SIMD */

// ---------------- Threefry-2x32 (20 rounds), exactly JAX's ----------------
__device__ __forceinline__ void tf2x32(uint32_t k0, uint32_t k1,
                                       uint32_t c0, uint32_t c1,
                                       uint32_t& o0, uint32_t& o1) {
  uint32_t ks2 = k0 ^ k1 ^ 0x1BD11BDAu;
  uint32_t x0 = c0 + k0, x1 = c1 + k1;
#define TF_R(r) { x0 += x1; x1 = ((x1 << (r)) | (x1 >> (32 - (r)))); x1 ^= x0; }
  TF_R(13) TF_R(15) TF_R(26) TF_R(6)
  x0 += k1; x1 += ks2 + 1u;
  TF_R(17) TF_R(29) TF_R(16) TF_R(24)
  x0 += ks2; x1 += k0 + 2u;
  TF_R(13) TF_R(15) TF_R(26) TF_R(6)
  x0 += k0; x1 += k1 + 3u;
  TF_R(17) TF_R(29) TF_R(16) TF_R(24)
  x0 += k1; x1 += ks2 + 4u;
  TF_R(13) TF_R(15) TF_R(26) TF_R(6)
  x0 += ks2; x1 += k0 + 5u;
#undef TF_R
  o0 = x0; o1 = x1;
}

// XLA ErfInv32 (Giles single-precision polynomial)
__device__ __forceinline__ float erfinv_f(float x) {
  float w = -log1pf(-x * x);
  float p;
  if (w < 5.0f) {
    w -= 2.5f;
    p = 2.81022636e-08f;
    p = fmaf(p, w, 3.43273939e-07f);
    p = fmaf(p, w, -3.5233877e-06f);
    p = fmaf(p, w, -4.39150654e-06f);
    p = fmaf(p, w, 0.00021858087f);
    p = fmaf(p, w, -0.00125372503f);
    p = fmaf(p, w, -0.00417768164f);
    p = fmaf(p, w, 0.246640727f);
    p = fmaf(p, w, 1.50140941f);
  } else {
    w = sqrtf(w) - 3.0f;
    p = -0.000200214257f;
    p = fmaf(p, w, 0.000100950558f);
    p = fmaf(p, w, 0.00134934322f);
    p = fmaf(p, w, -0.00367342844f);
    p = fmaf(p, w, 0.00573950773f);
    p = fmaf(p, w, -0.0076224613f);
    p = fmaf(p, w, 0.00943887047f);
    p = fmaf(p, w, 1.00167406f);
    p = fmaf(p, w, 2.83297682f);
  }
  return p * x;
}

__device__ __forceinline__ float sigmoid_f(float x) { return 1.0f / (1.0f + expf(-x)); }
__device__ __forceinline__ float softplus_f(float x) {
  return (x > 0.0f) ? (x + log1pf(expf(-x))) : log1pf(expf(x));
}

// 512 blocks x 512 threads. Block owns 8 batch rows.
// thread: r = tid&7 (row), idx = tid>>3 (0..63 slice).
// idx owns: 2 hidden neurons [idx*2, idx*2+2);
//           latent kd=idx>>1 (even idx: mu-chain, odd idx: sigma-chain, shfl-pair);
//           y: dot c=idx>>2 quarter q=idx&3 (c<10), shuffle-tree reduce.
// pn: full sequential 128-FMA chain in EVERY thread (bit-exact, feeds argmax).
__launch_bounds__(THREADS, 4)
__global__ void vrnn_kernel(const float* __restrict__ x, const float* __restrict__ sx,
                            const float* __restrict__ Wih, const float* __restrict__ Whh,
                            const float* __restrict__ bih, const float* __restrict__ bhh,
                            const float* __restrict__ We, const float* __restrict__ be,
                            const float* __restrict__ Wl, const float* __restrict__ bl,
                            const float* __restrict__ Wo, const float* __restrict__ bo,
                            const float* __restrict__ Whalt, const float* __restrict__ bhalt,
                            float* __restrict__ out) {
  __shared__ float sh_hA[ROWS][132];     // h carry / hb  (P1,P4 read; P3 write)
  __shared__ float sh_hB[ROWS][132];     // h_gru         (P1 write; P2 read)
  __shared__ float sh_z[ROWS][36];
  __shared__ float sh_x[ROWS][68];
  __shared__ uint32_t sh_keys[T_ * M_][2];

  const int tid = threadIdx.x;
  const int r = tid & (ROWS - 1);
  const int idx = tid >> 3;              // 0..63
  const int i0 = idx * 2;                // hidden slice (2 neurons)
  const int kd = idx >> 1;               // latent neuron
  const int role = idx & 1;              // 0: mu, 1: sigma
  const int c = idx >> 2;                // y dot index
  const int q = idx & 3;                 // y quarter
  const int b = (int)blockIdx.x * ROWS + r;

  // JAX >=0.5 partitionable split: key_q = threefry(key, (0, q))
  if (tid < T_ * M_) {
    uint32_t o0, o1;
    tf2x32(0u, 42u, 0u, (uint32_t)tid, o0, o1);
    sh_keys[tid][0] = o0;
    sh_keys[tid][1] = o1;
  }

  // init h carry = sx (coalesced: 1024 elems, 512 threads x 2)
#pragma unroll
  for (int e = tid; e < ROWS * H_; e += THREADS)
    sh_hA[e >> 7][e & 127] = sx[(int)blockIdx.x * ROWS * H_ + e];
  __syncthreads();

#pragma unroll 1
  for (int t = 0; t < T_; ++t) {
    // ---- stage x_t for the block's rows ----
    {
      int row = tid >> 6, d = tid & 63;
      sh_x[row][d] = x[((int)blockIdx.x * ROWS + row) * (D_ * T_) + d * T_ + t];
    }
    __syncthreads();

    // ---- per-step gi for owned neurons (6 Wih rows, x from LDS broadcast) ----
    float gi[6];
#pragma unroll 1
    for (int g = 0; g < 3; ++g) {
#pragma unroll
      for (int ii = 0; ii < 2; ++ii) {
        int j = g * H_ + i0 + ii;
        float acc = bih[j];
        const float* wp = Wih + j * D_;
#pragma unroll 4
        for (int kk = 0; kk < D_ / 4; ++kk) {
          float4 xv = *(const float4*)&sh_x[r][kk * 4];
          float4 wv = *(const float4*)(wp + kk * 4);
          acc = fmaf(wv.x, xv.x, acc);
          acc = fmaf(wv.y, xv.y, acc);
          acc = fmaf(wv.z, xv.z, acc);
          acc = fmaf(wv.w, xv.w, acc);
        }
        gi[g * 2 + ii] = acc;
      }
    }

    float st[2] = {0.0f, 0.0f};
    float yt = 0.0f;
    float csum = 0.0f, pmprev = 0.0f, rt = 0.0f;
    int nt = -1;

#pragma unroll 1
    for (int m = 0; m < M_; ++m) {
      // ---- P1: gh for 2 neurons (stream h from A), gate-combine -> write B ----
      {
        float a[6];
#pragma unroll
        for (int g = 0; g < 3; ++g)
#pragma unroll
          for (int ii = 0; ii < 2; ++ii) a[g * 2 + ii] = bhh[g * H_ + i0 + ii];
        const float* w0 = Whh + (0 * H_ + i0) * H_;
        const float* w1 = Whh + (1 * H_ + i0) * H_;
        const float* w2 = Whh + (2 * H_ + i0) * H_;
#pragma unroll 2
        for (int kk = 0; kk < H_ / 4; ++kk) {
          float4 hv = *(const float4*)&sh_hA[r][kk * 4];
#pragma unroll
          for (int ii = 0; ii < 2; ++ii) {
            float4 wv;
            wv = *(const float4*)(w0 + ii * H_ + kk * 4);
            a[0 + ii] = fmaf(wv.x, hv.x, a[0 + ii]);
            a[0 + ii] = fmaf(wv.y, hv.y, a[0 + ii]);
            a[0 + ii] = fmaf(wv.z, hv.z, a[0 + ii]);
            a[0 + ii] = fmaf(wv.w, hv.w, a[0 + ii]);
            wv = *(const float4*)(w1 + ii * H_ + kk * 4);
            a[2 + ii] = fmaf(wv.x, hv.x, a[2 + ii]);
            a[2 + ii] = fmaf(wv.y, hv.y, a[2 + ii]);
            a[2 + ii] = fmaf(wv.z, hv.z, a[2 + ii]);
            a[2 + ii] = fmaf(wv.w, hv.w, a[2 + ii]);
            wv = *(const float4*)(w2 + ii * H_ + kk * 4);
            a[4 + ii] = fmaf(wv.x, hv.x, a[4 + ii]);
            a[4 + ii] = fmaf(wv.y, hv.y, a[4 + ii]);
            a[4 + ii] = fmaf(wv.z, hv.z, a[4 + ii]);
            a[4 + ii] = fmaf(wv.w, hv.w, a[4 + ii]);
          }
        }
#pragma unroll
        for (int ii = 0; ii < 2; ++ii) {
          float rg = sigmoid_f(gi[ii] + a[ii]);
          float zg = sigmoid_f(gi[2 + ii] + a[2 + ii]);
          float ng = tanhf(fmaf(rg, a[4 + ii], gi[4 + ii]));
          float hprev = sh_hA[r][i0 + ii];
          sh_hB[r][i0 + ii] = (1.0f - zg) * ng + zg * hprev;
        }
      }
      __syncthreads();

      // ---- P2: latent dot (mu or sigma chain per role), pair-combine, z draw ----
      {
        int wrow = role ? (K_ + kd) : kd;
        float acc = be[wrow];
        const float* wm = We + wrow * H_;
#pragma unroll 2
        for (int kk = 0; kk < H_ / 4; ++kk) {
          float4 hv = *(const float4*)&sh_hB[r][kk * 4];
          float4 wv = *(const float4*)(wm + kk * 4);
          acc = fmaf(wv.x, hv.x, acc);
          acc = fmaf(wv.y, hv.y, acc);
          acc = fmaf(wv.z, hv.z, acc);
          acc = fmaf(wv.w, hv.w, acc);
        }
        float accP = __shfl_xor(acc, 8);   // partner's chain (idx^1, same wave)
        if (role == 0) {
          float accM = acc, accS = accP;
          float sg = softplus_f(accS - 5.0f);
          uint32_t key0 = sh_keys[t * M_ + m][0];
          uint32_t key1 = sh_keys[t * M_ + m][1];
          uint32_t e = (uint32_t)b * 32u + (uint32_t)kd;
          uint32_t r0, r1;
          tf2x32(key0, key1, 0u, e, r0, r1);
          uint32_t bits = r0 ^ r1;
          float f = __uint_as_float((bits >> 9) | 0x3f800000u) - 1.0f;
          float u = fmaf(f, 2.0f, -0.99999994f);
          u = fmaxf(-0.99999994f, u);
          float eps = 1.41421356f * erfinv_f(u);
          sh_z[r][kd] = fmaf(eps, sg, accM);
        }
      }
      __syncthreads();

      // ---- P3: hb = tanh(z @ Wl.T + bl) for 2 neurons -> write A ----
      float hn[2];
      {
        float zr[K_];
#pragma unroll
        for (int qz = 0; qz < K_ / 4; ++qz) {
          float4 zv = *(const float4*)&sh_z[r][qz * 4];
          zr[qz * 4] = zv.x; zr[qz * 4 + 1] = zv.y;
          zr[qz * 4 + 2] = zv.z; zr[qz * 4 + 3] = zv.w;
        }
#pragma unroll
        for (int ii = 0; ii < 2; ++ii) {
          int i = i0 + ii;
          float v = bl[i];
          const float* wl = Wl + i * K_;
#pragma unroll
          for (int k = 0; k < K_; ++k) v = fmaf(wl[k], zr[k], v);
          hn[ii] = tanhf(v);
          sh_hA[r][i] = hn[ii];
        }
      }
      __syncthreads();

      // ---- P4: pn (full chain, all threads), y quarter + shuffle reduce ----
      {
        float pa = bhalt[0];
#pragma unroll 2
        for (int kk = 0; kk < H_ / 4; ++kk) {
          float4 hv = *(const float4*)&sh_hA[r][kk * 4];
          float4 av = *(const float4*)(Whalt + kk * 4);
          pa = fmaf(av.x, hv.x, pa); pa = fmaf(av.y, hv.y, pa);
          pa = fmaf(av.z, hv.z, pa); pa = fmaf(av.w, hv.w, pa);
        }
        float pn = sigmoid_f(pa);

        float yv = 0.0f;
        if (c < NC_) {
          float yq = (q == 0) ? bo[c] : 0.0f;
          const float* wo = Wo + c * H_ + q * 32;
#pragma unroll
          for (int kk = 0; kk < 8; ++kk) {
            float4 hv = *(const float4*)&sh_hA[r][q * 32 + kk * 4];
            float4 ov = *(const float4*)(wo + kk * 4);
            yq = fmaf(ov.x, hv.x, yq); yq = fmaf(ov.y, hv.y, yq);
            yq = fmaf(ov.z, hv.z, yq); yq = fmaf(ov.w, hv.w, yq);
          }
          yq += __shfl_xor(yq, 8);    // combine q^1
          yq += __shfl_xor(yq, 16);   // combine q^2
          yv = yq;                    // all 4 lanes of group hold full dot
        }

        csum += pn;
        float pm = (m == M_ - 1) ? 1.0f : fminf(1.0f, csum);
        if (nt < 0 && (csum >= 1.0f || m == M_ - 1)) {
          nt = m;
          rt = (m == 0) ? 0.0f : (1.0f - pmprev);
        }
        float ph = pm - pmprev;
        pmprev = pm;
#pragma unroll
        for (int ii = 0; ii < 2; ++ii) st[ii] = fmaf(ph, hn[ii], st[ii]);
        yt = fmaf(ph, yv, yt);
      }
      // no barrier: next P1 reads A (stable) and writes B (last read 2 barriers ago)
    }  // ticks

    // ---- step end: st becomes next h carry; write outputs ----
    __syncthreads();   // all P4 reads of A complete before overwrite
#pragma unroll
    for (int ii = 0; ii < 2; ++ii) sh_hA[r][i0 + ii] = st[ii];
    if (c < NC_ && q == 0) out[b * (NC_ * T_) + c * T_ + t] = yt;
    if (idx == 40) {
      out[P_OFF + b * T_ + t] = (float)nt + rt;
      out[N_OFF + b * T_ + t] = (float)nt;
    }
    if (t == T_ - 1) {
#pragma unroll
      for (int ii = 0; ii < 2; ++ii)
        out[SX_OFF + b * H_ + i0 + ii] = st[ii];
    }
    __syncthreads();   // new carry + sh_x reuse safe before next step
  }  // steps
}

extern "C" void kernel_launch(void* const* d_in, const int* in_sizes, int n_in,
                              void* d_out, int out_size, void* d_ws, size_t ws_size,
                              hipStream_t stream) {
  (void)in_sizes; (void)n_in; (void)out_size; (void)d_ws; (void)ws_size;
  const float* x     = (const float*)d_in[0];
  const float* sx    = (const float*)d_in[1];
  const float* Wih   = (const float*)d_in[2];
  const float* Whh   = (const float*)d_in[3];
  const float* bih   = (const float*)d_in[4];
  const float* bhh   = (const float*)d_in[5];
  const float* We    = (const float*)d_in[6];
  const float* be    = (const float*)d_in[7];
  const float* Wl    = (const float*)d_in[8];
  const float* bl    = (const float*)d_in[9];
  const float* Wo    = (const float*)d_in[10];
  const float* bo    = (const float*)d_in[11];
  const float* Whalt = (const float*)d_in[12];
  const float* bhalt = (const float*)d_in[13];
  float* out = (float*)d_out;

  vrnn_kernel<<<dim3(B_ / ROWS), dim3(THREADS), 0, stream>>>(x, sx, Wih, Whh, bih, bhh,
                                                             We, be, Wl, bl, Wo, bo,
                                                             Whalt, bhalt, out);
}